// Round 4
// baseline (1490.034 us; speedup 1.0000x reference)
//
#include <hip/hip_runtime.h>
#include <cstdint>

typedef _Float16 f16;
typedef _Float16 h8 __attribute__((ext_vector_type(8)));
typedef _Float16 h4 __attribute__((ext_vector_type(4)));
typedef float f4 __attribute__((ext_vector_type(4)));

#define NB 1024
#define NT 250
#define IND 158
#define KP0 160
#define NH 128
#define NG 512
#define LN_EPS 1e-5f

__device__ __forceinline__ float fast_sigmoid(float x) {
  float e = __builtin_amdgcn_exp2f(-1.44269504f * x);
  return __builtin_amdgcn_rcpf(1.f + e);
}
__device__ __forceinline__ float fast_tanh(float x) {
  float e = __builtin_amdgcn_exp2f(2.88539008f * x);
  return 1.f - 2.f * __builtin_amdgcn_rcpf(e + 1.f);
}

// ---------------- K0: weight fp32 -> f16 with padding/zero-fill ----------------
__global__ __launch_bounds__(256) void k_prep(const float* __restrict__ src, f16* __restrict__ dst,
                                              int srows, int scols, int dcols, int total) {
  int i = blockIdx.x * 256 + threadIdx.x;
  if (i >= total) return;
  int r = i / dcols, c = i - r * dcols;
  float v = (r < srows && c < scols) ? src[r * scols + c] : 0.f;
  dst[i] = (f16)v;
}

// ---------------- LayerNorm -> xn f16 [B][tc][160] ----------------
__global__ __launch_bounds__(256) void k_ln(const float* __restrict__ x, const float* __restrict__ gamma,
                                            const float* __restrict__ beta, f16* __restrict__ xn,
                                            int t0, int tc) {
  int tid = threadIdx.x;
  int sub = tid & 7;            // 8 threads per row
  int rloc = tid >> 3;          // 32 rows per block
  long long rowi = (long long)blockIdx.x * 32 + rloc;   // row over [B][tc]
  int b = (int)(rowi / tc), t = (int)(rowi % tc);
  const float* xr = x + ((long long)b * NT + (t0 + t)) * IND;
  float vals[20];
  float s = 0.f, ss = 0.f;
#pragma unroll
  for (int i = 0; i < 20; i++) {
    int k = sub + 8 * i;
    float v = (k < IND) ? xr[k] : 0.f;
    vals[i] = v; s += v; ss += v * v;
  }
  s += __shfl_xor(s, 1); ss += __shfl_xor(ss, 1);
  s += __shfl_xor(s, 2); ss += __shfl_xor(ss, 2);
  s += __shfl_xor(s, 4); ss += __shfl_xor(ss, 4);
  float mu = s * (1.f / IND);
  float var = ss * (1.f / IND) - mu * mu;
  float rs = rsqrtf(var + LN_EPS);
  f16* outr = xn + ((long long)b * tc + t) * KP0;
#pragma unroll
  for (int i = 0; i < 20; i++) {
    int k = sub + 8 * i;
    float v = (k < IND) ? (vals[i] - mu) * rs * gamma[k] + beta[k] : 0.f;
    outr[k] = (f16)v;   // k in [0,160): zero-fills K-pad
  }
}

// ---------------- xg = inp @ W^T + bias  (MFMA f16, W rows as M, samples as N) ----------------
// Output layout: [t][sample][ugrp:32][g:4][r:4] f16  (per-lane 32B chunks for the fused consumer)
template <int KP>
__global__ __launch_bounds__(256, 1) void k_gates(const f16* __restrict__ inp, long long tStride,
                                                  long long rowStride, const f16* __restrict__ W,
                                                  const float* __restrict__ bias, f16* __restrict__ xg) {
  constexpr int KPP = KP + 8;      // pad: row stride multiple of 16B
  constexpr int KS = KP / 32;
  extern __shared__ f16 lds[];
  f16* Wl = lds;                   // [128][KPP]  W rows (M = gate rows)
  f16* Il = lds + 128 * KPP;       // [128][KPP]  input rows (N = samples)
  int t = blockIdx.x, gs = blockIdx.y, bs = blockIdx.z;
  int tid = threadIdx.x;
  {
    int row = tid >> 1, half = tid & 1;
    const float4* srcw = (const float4*)(W + (gs * 128 + row) * KP) + half * (KP / 16);
    float4* dstw = (float4*)(Wl + row * KPP) + half * (KP / 16);
#pragma unroll
    for (int i = 0; i < KP / 16; i++) dstw[i] = srcw[i];
    const float4* srci = (const float4*)(inp + (long long)t * tStride + (long long)(bs * 128 + row) * rowStride) + half * (KP / 16);
    float4* dsti = (float4*)(Il + row * KPP) + half * (KP / 16);
#pragma unroll
    for (int i = 0; i < KP / 16; i++) dsti[i] = srci[i];
  }
  __syncthreads();
  int w = tid >> 6, lane = tid & 63, l15 = lane & 15, q = lane >> 4;
  h8 bf[2][KS];
#pragma unroll
  for (int nt = 0; nt < 2; nt++)
#pragma unroll
    for (int ks = 0; ks < KS; ks++)
      bf[nt][ks] = *(const h8*)(Il + (32 * w + 16 * nt + l15) * KPP + 32 * ks + 8 * q);
  f4 acc[8][2];
#pragma unroll
  for (int mt = 0; mt < 8; mt++) {
    float4 b4 = *(const float4*)(bias + gs * 128 + 16 * mt + 4 * q);
#pragma unroll
    for (int nt = 0; nt < 2; nt++) acc[mt][nt] = (f4){b4.x, b4.y, b4.z, b4.w};
  }
#pragma unroll
  for (int mt = 0; mt < 8; mt++) {
    h8 af[KS];
#pragma unroll
    for (int ks = 0; ks < KS; ks++)
      af[ks] = *(const h8*)(Wl + (16 * mt + l15) * KPP + 32 * ks + 8 * q);
#pragma unroll
    for (int nt = 0; nt < 2; nt++)
#pragma unroll
      for (int ks = 0; ks < KS; ks++)
        acc[mt][nt] = __builtin_amdgcn_mfma_f32_16x16x32_f16(af[ks], bf[nt][ks], acc[mt][nt], 0, 0, 0);
  }
  // gate-row u = 16mt+4q+r -> chunk [u>>2][gate=gs][r]
#pragma unroll
  for (int mt = 0; mt < 8; mt++)
#pragma unroll
    for (int nt = 0; nt < 2; nt++) {
      h4 o4;
#pragma unroll
      for (int r = 0; r < 4; r++) o4[r] = (f16)acc[mt][nt][r];
      long long sample = bs * 128 + 32 * w + 16 * nt + l15;
      *(h4*)(xg + ((long long)t * NB + sample) * NG + (4 * mt + q) * 16 + gs * 4) = o4;
    }
}

// ---------------- Fused 2-layer LSTM: 256 thr, 4 waves, 32 units/wave, ALL weights in regs ----------------
// xg: [tc][1024][32][4][4] f16 (layer-0 pre-gates incl. b0)
__global__ __launch_bounds__(256, 1) void k_fused(const f16* __restrict__ xg, const f16* __restrict__ Whh0f,
                                                  const f16* __restrict__ Wih1f, const f16* __restrict__ Whh1f,
                                                  const float* __restrict__ b1, f16* __restrict__ hseq,
                                                  float* __restrict__ ch0, float* __restrict__ cc0,
                                                  float* __restrict__ ch1, float* __restrict__ cc1,
                                                  int tc, int first) {
  __shared__ f16 h0b[2][16][136];
  __shared__ f16 h1b[2][16][136];
  int tid = threadIdx.x;
  int w = tid >> 6, lane = tid & 63, l15 = lane & 15, q = lane >> 4;
  int b0 = blockIdx.x * 16;

  // h-state init: h0(-1) -> h0b[0]; h1(-1) -> h1b[1]; other parity zeroed
  for (int i = tid; i < 2176; i += 256) {
    int n = i / 136, k = i - n * 136;
    float h0v = (!first && k < NH) ? ch0[(b0 + n) * NH + k] : 0.f;
    float h1v = (!first && k < NH) ? ch1[(b0 + n) * NH + k] : 0.f;
    ((f16*)h0b)[i] = (f16)h0v;
    ((f16*)h0b)[2176 + i] = (f16)0.f;
    ((f16*)h1b)[i] = (f16)0.f;
    ((f16*)h1b)[2176 + i] = (f16)h1v;
  }
  float c0r[2][4], c1r[2][4];
#pragma unroll
  for (int mt = 0; mt < 2; mt++)
#pragma unroll
    for (int r = 0; r < 4; r++) {
      int u = 32 * w + 16 * mt + 4 * q + r;
      c0r[mt][r] = first ? 0.f : cc0[(b0 + l15) * NH + u];
      c1r[mt][r] = first ? 0.f : cc1[(b0 + l15) * NH + u];
    }
  // register-resident weights: Whh0, Wih1, Whh1 (32 units/wave each, 384 regs)
  h8 af0[2][4][4], af1[2][4][4], afhh[2][4][4];
#pragma unroll
  for (int mt = 0; mt < 2; mt++)
#pragma unroll
    for (int g = 0; g < 4; g++)
#pragma unroll
      for (int ks = 0; ks < 4; ks++) {
        int row = 128 * g + 32 * w + 16 * mt + l15;
        af0[mt][g][ks]  = *(const h8*)(Whh0f + row * 136 + 32 * ks + 8 * q);
        af1[mt][g][ks]  = *(const h8*)(Wih1f + row * 128 + 32 * ks + 8 * q);
        afhh[mt][g][ks] = *(const h8*)(Whh1f + row * 136 + 32 * ks + 8 * q);
      }
  h4 bias_h[2][4];   // b1 packed f16 per (mt, gate)
#pragma unroll
  for (int mt = 0; mt < 2; mt++)
#pragma unroll
    for (int g = 0; g < 4; g++) {
      float4 b4 = *(const float4*)(b1 + 128 * g + 32 * w + 16 * mt + 4 * q);
      bias_h[mt][g] = (h4){(f16)b4.x, (f16)b4.y, (f16)b4.z, (f16)b4.w};
    }
  __syncthreads();

  const f16* xgb = xg + (long long)(b0 + l15) * NG + (8 * w + q) * 16;  // + mt*64
  const long long tstep = (long long)NB * NG;
  h8 xc0[2][2], xn0[2][2];   // per mt: 32B chunk = 2 h8
#pragma unroll
  for (int mt = 0; mt < 2; mt++) {
    xc0[mt][0] = *(const h8*)(xgb + 64 * mt);
    xc0[mt][1] = *(const h8*)(xgb + 64 * mt + 8);
  }
  h4 h0last[2], h1last[2];
  const int ldsrow = l15 * 136;

  for (int n = 0; n <= tc; n++) {
    int p = n & 1;
    // prefetch next timestep's pre-gates
    if (n + 1 < tc) {
      const f16* xr = xgb + (long long)(n + 1) * tstep;
#pragma unroll
      for (int mt = 0; mt < 2; mt++) {
        xn0[mt][0] = *(const h8*)(xr + 64 * mt);
        xn0[mt][1] = *(const h8*)(xr + 64 * mt + 8);
      }
    }
    // h0(n-1) fragments — used by layer-0 recurrence AND layer-1 ih-input
    h8 bf0[4];
#pragma unroll
    for (int ks = 0; ks < 4; ks++)
      bf0[ks] = *(const h8*)(&h0b[p][0][0] + ldsrow + 32 * ks + 8 * q);
    if (n < tc) {   // ---- layer 0, step t = n ----
      f4 acc[2][4];
#pragma unroll
      for (int mt = 0; mt < 2; mt++)
#pragma unroll
        for (int g = 0; g < 4; g++)
#pragma unroll
          for (int r = 0; r < 4; r++) {
            int idx = 4 * g + r;
            acc[mt][g][r] = (float)((idx < 8) ? xc0[mt][0][idx] : xc0[mt][1][idx - 8]);
          }
#pragma unroll
      for (int mt = 0; mt < 2; mt++)
#pragma unroll
        for (int g = 0; g < 4; g++)
#pragma unroll
          for (int ks = 0; ks < 4; ks++)
            acc[mt][g] = __builtin_amdgcn_mfma_f32_16x16x32_f16(af0[mt][g][ks], bf0[ks], acc[mt][g], 0, 0, 0);
#pragma unroll
      for (int mt = 0; mt < 2; mt++) {
        h4 hv;
#pragma unroll
        for (int r = 0; r < 4; r++) {
          float iv = fast_sigmoid(acc[mt][0][r]);
          float fv = fast_sigmoid(acc[mt][1][r]);
          float gv = fast_tanh(acc[mt][2][r]);
          float ov = fast_sigmoid(acc[mt][3][r]);
          float cc = fv * c0r[mt][r] + iv * gv;
          c0r[mt][r] = cc;
          hv[r] = (f16)(ov * fast_tanh(cc));
        }
        *(h4*)(&h0b[1 - p][0][0] + ldsrow + 32 * w + 16 * mt + 4 * q) = hv;
        h0last[mt] = hv;
      }
    }
    if (n >= 1) {   // ---- layer 1, step t = n-1 ----
      h8 bf1[4];
#pragma unroll
      for (int ks = 0; ks < 4; ks++)
        bf1[ks] = *(const h8*)(&h1b[p][0][0] + ldsrow + 32 * ks + 8 * q);
      f4 acc[2][4];
#pragma unroll
      for (int mt = 0; mt < 2; mt++)
#pragma unroll
        for (int g = 0; g < 4; g++)
#pragma unroll
          for (int r = 0; r < 4; r++) acc[mt][g][r] = (float)bias_h[mt][g][r];
#pragma unroll
      for (int mt = 0; mt < 2; mt++)
#pragma unroll
        for (int g = 0; g < 4; g++)
#pragma unroll
          for (int ks = 0; ks < 4; ks++)
            acc[mt][g] = __builtin_amdgcn_mfma_f32_16x16x32_f16(af1[mt][g][ks], bf0[ks], acc[mt][g], 0, 0, 0);
#pragma unroll
      for (int mt = 0; mt < 2; mt++)
#pragma unroll
        for (int g = 0; g < 4; g++)
#pragma unroll
          for (int ks = 0; ks < 4; ks++)
            acc[mt][g] = __builtin_amdgcn_mfma_f32_16x16x32_f16(afhh[mt][g][ks], bf1[ks], acc[mt][g], 0, 0, 0);
#pragma unroll
      for (int mt = 0; mt < 2; mt++) {
        h4 hv;
#pragma unroll
        for (int r = 0; r < 4; r++) {
          float iv = fast_sigmoid(acc[mt][0][r]);
          float fv = fast_sigmoid(acc[mt][1][r]);
          float gv = fast_tanh(acc[mt][2][r]);
          float ov = fast_sigmoid(acc[mt][3][r]);
          float cc = fv * c1r[mt][r] + iv * gv;
          c1r[mt][r] = cc;
          hv[r] = (f16)(ov * fast_tanh(cc));
        }
        *(h4*)(&h1b[1 - p][0][0] + ldsrow + 32 * w + 16 * mt + 4 * q) = hv;
        *(h4*)(hseq + ((long long)(n - 1) * NB + b0 + l15) * NH + 32 * w + 16 * mt + 4 * q) = hv;
        h1last[mt] = hv;
      }
    }
#pragma unroll
    for (int mt = 0; mt < 2; mt++) { xc0[mt][0] = xn0[mt][0]; xc0[mt][1] = xn0[mt][1]; }
    // LDS-only barrier: xg prefetches / hseq stores stay in flight
    asm volatile("s_waitcnt lgkmcnt(0)\n\ts_barrier" ::: "memory");
  }
#pragma unroll
  for (int mt = 0; mt < 2; mt++)
#pragma unroll
    for (int r = 0; r < 4; r++) {
      int idx = (b0 + l15) * NH + 32 * w + 16 * mt + 4 * q + r;
      cc0[idx] = c0r[mt][r];
      cc1[idx] = c1r[mt][r];
      ch0[idx] = (float)h0last[mt][r];
      ch1[idx] = (float)h1last[mt][r];
    }
}

// ---------------- out = relu(h1 @ Wp1^T + bp1) @ Wp2^T + bp2 ----------------
__global__ __launch_bounds__(256, 1) void k_proj(const f16* __restrict__ hseq, const f16* __restrict__ Wp1f,
                                                 const f16* __restrict__ Wp2f, const float* __restrict__ bp1,
                                                 const float* __restrict__ bp2, float* __restrict__ out,
                                                 int tc, int t0) {
  extern __shared__ f16 lds[];
  f16* hl = lds;                  // [128][136]
  f16* w1 = hl + 128 * 136;       // [64][136]
  f16* w2 = w1 + 64 * 136;        // [32][72]
  f16* pl = w2 + 32 * 72;         // [128][72]
  int t = blockIdx.x, bs = blockIdx.y;
  int tid = threadIdx.x;
  {
    int b = tid >> 1, half = tid & 1;
    const float4* s = (const float4*)(hseq + ((long long)t * NB + bs * 128 + b) * NH) + half * 8;
    float4* d = (float4*)(hl + b * 136) + half * 8;
#pragma unroll
    for (int i = 0; i < 8; i++) d[i] = s[i];
    if (tid < 128) {
      int row = tid >> 1;
      const float4* sw = (const float4*)(Wp1f + row * 128) + (tid & 1) * 8;
      float4* dw = (float4*)(w1 + row * 136) + (tid & 1) * 8;
#pragma unroll
      for (int i = 0; i < 8; i++) dw[i] = sw[i];
    } else if (tid < 192) {
      int t2 = tid - 128;
      int row = t2 >> 1;
      const float4* sw = (const float4*)(Wp2f + row * 64) + (t2 & 1) * 4;
      float4* dw = (float4*)(w2 + row * 72) + (t2 & 1) * 4;
#pragma unroll
      for (int i = 0; i < 4; i++) dw[i] = sw[i];
    }
  }
  __syncthreads();
  int w = tid >> 6, lane = tid & 63, l15 = lane & 15, q = lane >> 4;
  {
    h8 bf[4];
#pragma unroll
    for (int ks = 0; ks < 4; ks++)
      bf[ks] = *(const h8*)(w1 + (16 * w + l15) * 136 + 32 * ks + 8 * q);
    float bv = bp1[16 * w + l15];
#pragma unroll
    for (int mt = 0; mt < 8; mt++) {
      f4 acc = (f4){bv, bv, bv, bv};
#pragma unroll
      for (int ks = 0; ks < 4; ks++) {
        h8 a = *(const h8*)(hl + (16 * mt + l15) * 136 + 32 * ks + 8 * q);
        acc = __builtin_amdgcn_mfma_f32_16x16x32_f16(a, bf[ks], acc, 0, 0, 0);
      }
#pragma unroll
      for (int r = 0; r < 4; r++) {
        float v = acc[r] > 0.f ? acc[r] : 0.f;
        pl[(16 * mt + 4 * q + r) * 72 + 16 * w + l15] = (f16)v;
      }
    }
  }
  __syncthreads();
  {
    int nt = w & 1;
    int o = 16 * nt + l15;
    h8 bf2[2];
#pragma unroll
    for (int ks = 0; ks < 2; ks++)
      bf2[ks] = *(const h8*)(w2 + o * 72 + 32 * ks + 8 * q);
    float bv = (o < 22) ? bp2[o] : 0.f;
#pragma unroll
    for (int mi = 0; mi < 4; mi++) {
      int mt = (w >> 1) * 4 + mi;
      f4 acc = (f4){bv, bv, bv, bv};
#pragma unroll
      for (int ks = 0; ks < 2; ks++) {
        h8 a = *(const h8*)(pl + (16 * mt + l15) * 72 + 32 * ks + 8 * q);
        acc = __builtin_amdgcn_mfma_f32_16x16x32_f16(a, bf2[ks], acc, 0, 0, 0);
      }
      if (o < 22) {
#pragma unroll
        for (int r = 0; r < 4; r++) {
          int brow = bs * 128 + 16 * mt + 4 * q + r;
          out[((long long)brow * NT + (t0 + t)) * 22 + o] = acc[r];
        }
      }
    }
  }
}

extern "C" void kernel_launch(void* const* d_in, const int* in_sizes, int n_in,
                              void* d_out, int out_size, void* d_ws, size_t ws_size,
                              hipStream_t stream) {
  const float* x    = (const float*)d_in[0];
  const float* gam  = (const float*)d_in[1];
  const float* bet  = (const float*)d_in[2];
  const float* Wih0 = (const float*)d_in[3];
  const float* Whh0 = (const float*)d_in[4];
  const float* b0   = (const float*)d_in[5];
  const float* Wih1 = (const float*)d_in[6];
  const float* Whh1 = (const float*)d_in[7];
  const float* b1   = (const float*)d_in[8];
  const float* Wp1  = (const float*)d_in[9];
  const float* bp1  = (const float*)d_in[10];
  const float* Wp2  = (const float*)d_in[11];
  const float* bp2  = (const float*)d_in[12];
  float* out = (float*)d_out;

  uintptr_t base = (uintptr_t)d_ws;
  uintptr_t cur = base;
  auto alloc = [&](size_t bytes) { uintptr_t p = cur; cur += (bytes + 255) & ~(size_t)255; return (void*)p; };
  f16* Wih0f = (f16*)alloc((size_t)512 * 160 * 2);
  f16* Wih1f = (f16*)alloc((size_t)512 * 128 * 2);
  f16* Whh0f = (f16*)alloc((size_t)512 * 136 * 2);
  f16* Whh1f = (f16*)alloc((size_t)512 * 136 * 2);
  f16* Wp1f  = (f16*)alloc((size_t)64 * 128 * 2);
  f16* Wp2f  = (f16*)alloc((size_t)32 * 64 * 2);
  float* ch0 = (float*)alloc((size_t)1024 * 128 * 4);
  float* cc0 = (float*)alloc((size_t)1024 * 128 * 4);
  float* ch1 = (float*)alloc((size_t)1024 * 128 * 4);
  float* cc1 = (float*)alloc((size_t)1024 * 128 * 4);
  size_t fixed = cur - base;
  const size_t per_t = (size_t)1024 * 160 * 2 + (size_t)1024 * 512 * 2 + (size_t)1024 * 128 * 2;
  int tc = 1;
  const int cands[] = {250, 125, 50, 25, 10, 5, 2, 1};
  for (int cd : cands) {
    if (fixed + per_t * (size_t)cd + 4096 <= ws_size) { tc = cd; break; }
  }
  f16* xn  = (f16*)alloc((size_t)1024 * tc * 160 * 2);
  f16* xg  = (f16*)alloc((size_t)tc * 1024 * 512 * 2);
  f16* hsq = (f16*)alloc((size_t)tc * 1024 * 128 * 2);

  int lds1 = 2 * 128 * 168 * 2;                                // k_gates<160>
  int lds5 = (128 * 136 + 64 * 136 + 32 * 72 + 128 * 72) * 2;  // k_proj
  hipFuncSetAttribute(reinterpret_cast<const void*>(&k_gates<160>),
                      hipFuncAttributeMaxDynamicSharedMemorySize, lds1);
  hipFuncSetAttribute(reinterpret_cast<const void*>(&k_proj),
                      hipFuncAttributeMaxDynamicSharedMemorySize, lds5);

  // weight prep
  {
    struct Job { const float* s; f16* d; int sr, sc, dc, tot; };
    Job jobs[6] = {
        {Wih0, Wih0f, 512, 158, 160, 512 * 160},
        {Wih1, Wih1f, 512, 128, 128, 512 * 128},
        {Whh0, Whh0f, 512, 128, 136, 512 * 136},
        {Whh1, Whh1f, 512, 128, 136, 512 * 136},
        {Wp1,  Wp1f,  64, 128, 128, 64 * 128},
        {Wp2,  Wp2f,  22, 64, 64, 32 * 64},
    };
    for (int i = 0; i < 6; i++) {
      int g = (jobs[i].tot + 255) / 256;
      k_prep<<<g, 256, 0, stream>>>(jobs[i].s, jobs[i].d, jobs[i].sr, jobs[i].sc, jobs[i].dc, jobs[i].tot);
    }
  }

  int nch = NT / tc;
  for (int cidx = 0; cidx < nch; cidx++) {
    int t0 = cidx * tc;
    int first = (cidx == 0) ? 1 : 0;
    k_ln<<<dim3(1024 * tc / 32), 256, 0, stream>>>(x, gam, bet, xn, t0, tc);
    k_gates<160><<<dim3(tc, 4, 8), 256, lds1, stream>>>(xn, 160, (long long)tc * 160, Wih0f, b0, xg);
    k_fused<<<dim3(64), 256, 0, stream>>>(xg, Whh0f, Wih1f, Whh1f, b1, hsq, ch0, cc0, ch1, cc1, tc, first);
    k_proj<<<dim3(tc, 8), 256, lds5, stream>>>(hsq, Wp1f, Wp2f, bp1, bp2, out, tc, t0);
  }
}